// Round 3
// baseline (422.229 us; speedup 1.0000x reference)
//
#include <hip/hip_runtime.h>
#include <stdint.h>

// K-Planes hash-grid encoder, MI355X.
// Plan A (ws >= 201.4 MB): single gather kernel over all 48 (plane,level)
// tables. Block b -> XCD b&7 (HW round-robin, confirmed by round-2 FETCH
// collapse); each XCD walks 6 phases, one 4 MB table L2-resident per phase,
// schedule hand-balanced by L1-miss cost (lvl>=6 expensive). 4 pts/thread
// for gather MLP. Results stream to ws (48, NPTS) float2, no RMW.
// Combine kernel multiplies the 3 planes with coalesced reads and
// LDS-transposed coalesced writes.
// Plan B fallback (ws < 201.4 MB): round-2 3-pass + transpose (353 us).

#define NPTS   524288u
#define TSIZE  524288u      // 2^19 entries per (plane,level) table
#define TMASK  0x7FFFFu
#define PRIME1 2654435761u

// floor(16 * 1.3819^l) computed in float64 (matches numpy reference exactly)
__constant__ float c_res[16] = {
    16.f, 22.f, 30.f, 42.f, 58.f, 80.f, 111.f, 153.f,
    212.f, 294.f, 406.f, 561.f, 775.f, 1072.f, 1481.f, 2047.f
};

// slot = phase*8 + xcd  ->  group g = plane*16 + lvl.
// Balanced so each XCD's 6 groups have ~equal L1-miss cost
// (expensive lvl>=6: XCDs 0-5 get 4, XCDs 6-7 get 3 + mediums).
__constant__ uint8_t c_gmap[48] = {
     6,  8, 10, 12, 14, 38, 42, 45,
     7,  9, 11, 13, 15, 39, 43, 46,
    22, 24, 26, 28, 30, 40, 44, 47,
    23, 25, 27, 29, 31, 41,  5, 37,
     0,  1,  2,  3,  4, 32, 21, 35,
    16, 17, 18, 19, 20, 33, 34, 36
};

// ---------------- Plan A: 48-group gather, 4 pts/thread ---------------------
__global__ __launch_bounds__(256) void kplane_gather(
    const float* __restrict__ pts,
    const float2* __restrict__ tab,   // (3, 16, 2^19) float2
    float2* __restrict__ ws)          // (48, NPTS) float2, group-major
{
    const uint32_t b     = blockIdx.x;
    const uint32_t xcd   = b & 7u;
    const uint32_t s     = b >> 3;
    const uint32_t phase = s >> 9;           // 0..5
    const uint32_t chunk = s & 511u;         // 512 chunks x 1024 pts
    const uint32_t g     = c_gmap[phase * 8u + xcd];
    const uint32_t plane = g >> 4;
    const uint32_t lvl   = g & 15u;
    const float    res   = c_res[lvl];
    // plane combos: 0 -> (x,y), 1 -> (x,z), 2 -> (y,z)
    const uint32_t c0    = (plane == 2u) ? 1u : 0u;
    const uint32_t c1    = (plane == 0u) ? 1u : 2u;
    const uint32_t pt0   = chunk * 1024u + threadIdx.x;
    const uint32_t base  = g * TSIZE;

    float2 t00[4], t01[4], t10[4], t11[4];
    float  r0[4], r1[4];

#pragma unroll
    for (int k = 0; k < 4; ++k) {            // issue all 16 gathers first
        const uint32_t pt = pt0 + (uint32_t)k * 256u;
        const float s0 = pts[pt * 3u + c0] * res;
        const float s1 = pts[pt * 3u + c1] * res;
        const float f0 = floorf(s0);
        const float f1 = floorf(s1);
        r0[k] = s0 - f0;                     // exact f32 match to reference
        r1[k] = s1 - f1;
        const uint32_t u0  = (uint32_t)f0;
        const uint32_t hy0 = (uint32_t)f1 * PRIME1;
        const uint32_t hy1 = hy0 + PRIME1;   // (u1+1)*PRIME1 (wraps like ref)
        t00[k] = tab[base + (( u0       ^ hy0) & TMASK)];
        t01[k] = tab[base + (( u0       ^ hy1) & TMASK)];
        t10[k] = tab[base + (((u0 + 1u) ^ hy0) & TMASK)];
        t11[k] = tab[base + (((u0 + 1u) ^ hy1) & TMASK)];
    }
#pragma unroll
    for (int k = 0; k < 4; ++k) {
        const uint32_t pt = pt0 + (uint32_t)k * 256u;
        const float w00 = (1.f - r0[k]) * (1.f - r1[k]);
        const float w01 = (1.f - r0[k]) * r1[k];
        const float w10 = r0[k] * (1.f - r1[k]);
        const float w11 = r0[k] * r1[k];
        ws[g * NPTS + pt] = make_float2(
            w00 * t00[k].x + w01 * t01[k].x + w10 * t10[k].x + w11 * t11[k].x,
            w00 * t00[k].y + w01 * t01[k].y + w10 * t10[k].y + w11 * t11[k].y);
    }
}

// ---------------- Plan A: combine 3 planes, transpose via LDS ---------------
__global__ __launch_bounds__(256) void kplane_combine(
    const float2* __restrict__ ws,    // (48, NPTS)
    float2* __restrict__ out)         // (NPTS, 16)
{
    __shared__ float2 tile[16][65];          // 64-pt tile, +1 pad
    const uint32_t pt0 = blockIdx.x * 64u;
    const uint32_t t   = threadIdx.x;
    const uint32_t lr  = t >> 6;             // row sub-group 0..3
    const uint32_t ptl = t & 63u;

    float2 acc[4];
#pragma unroll
    for (int k = 0; k < 4; ++k) {            // rows lvl = k*4 + lr
        const uint32_t lvl = (uint32_t)k * 4u + lr;
        const float2 a = ws[( 0u + lvl) * NPTS + pt0 + ptl];
        const float2 b = ws[(16u + lvl) * NPTS + pt0 + ptl];
        const float2 c = ws[(32u + lvl) * NPTS + pt0 + ptl];
        acc[k] = make_float2(a.x * b.x * c.x, a.y * b.y * c.y);
        tile[lvl][ptl] = acc[k];
    }
    __syncthreads();
#pragma unroll
    for (int k = 0; k < 4; ++k) {            // coalesced pt-major writes
        const uint32_t e      = t + (uint32_t)k * 256u;   // 0..1023
        const uint32_t out_lv = e & 15u;
        const uint32_t out_pt = e >> 4;
        out[(pt0 + out_pt) * 16u + out_lv] = tile[out_lv][out_pt];
    }
}

// ---------------- Plan B fallback: round-2 3-pass + transpose ---------------
template <int P, bool FIRST>
__global__ __launch_bounds__(256) void kplane_pass(
    const float* __restrict__ pts,
    const float2* __restrict__ tab,
    float2* __restrict__ ws)          // (16, NPTS)
{
    const uint32_t b     = blockIdx.x;
    const uint32_t xcd   = b & 7u;
    const uint32_t s     = b >> 3;
    const uint32_t gi    = s >> 11;
    const uint32_t chunk = s & 2047u;
    const uint32_t lvl   = gi * 8u + xcd;
    const uint32_t pt    = chunk * 256u + threadIdx.x;

    constexpr int c0 = (P == 2) ? 1 : 0;
    constexpr int c1 = (P == 0) ? 1 : 2;

    const float a0  = pts[pt * 3u + c0];
    const float a1  = pts[pt * 3u + c1];
    const float res = c_res[lvl];

    const float s0 = a0 * res;
    const float s1 = a1 * res;
    const float f0 = floorf(s0);
    const float f1 = floorf(s1);
    const float r0 = s0 - f0;
    const float r1 = s1 - f1;
    const uint32_t u0 = (uint32_t)f0;
    const uint32_t hy0  = (uint32_t)f1 * PRIME1;
    const uint32_t hy1  = hy0 + PRIME1;
    const uint32_t base = ((uint32_t)P * 16u + lvl) * TSIZE;

    const float2 t00 = tab[base + (( u0       ^ hy0) & TMASK)];
    const float2 t01 = tab[base + (( u0       ^ hy1) & TMASK)];
    const float2 t10 = tab[base + (((u0 + 1u) ^ hy0) & TMASK)];
    const float2 t11 = tab[base + (((u0 + 1u) ^ hy1) & TMASK)];

    const float w00 = (1.f - r0) * (1.f - r1);
    const float w01 = (1.f - r0) * r1;
    const float w10 = r0 * (1.f - r1);
    const float w11 = r0 * r1;

    const float e0 = w00 * t00.x + w01 * t01.x + w10 * t10.x + w11 * t11.x;
    const float e1 = w00 * t00.y + w01 * t01.y + w10 * t10.y + w11 * t11.y;

    const uint32_t widx = lvl * NPTS + pt;
    if (FIRST) {
        ws[widx] = make_float2(e0, e1);
    } else {
        const float2 prev = ws[widx];
        ws[widx] = make_float2(prev.x * e0, prev.y * e1);
    }
}

__global__ __launch_bounds__(256) void kplane_transpose(
    const float2* __restrict__ ws, float2* __restrict__ out)
{
    const uint32_t tid = blockIdx.x * 256u + threadIdx.x;
    const uint32_t lvl = tid & 15u;
    const uint32_t pt  = tid >> 4;
    out[tid] = ws[lvl * NPTS + pt];
}

extern "C" void kernel_launch(void* const* d_in, const int* in_sizes, int n_in,
                              void* d_out, int out_size, void* d_ws, size_t ws_size,
                              hipStream_t stream) {
    const float*  pts = (const float*)d_in[0];
    const float2* tab = (const float2*)d_in[1];
    float2*       out = (float2*)d_out;

    const size_t wsA = (size_t)48 * NPTS * sizeof(float2);   // 201.3 MB
    const size_t wsB = (size_t)16 * NPTS * sizeof(float2);   //  67.1 MB
    dim3 block(256u);

    if (ws_size >= wsA) {
        float2* ws = (float2*)d_ws;
        dim3 ggrid(48u * (NPTS / 1024u));                    // 24576 blocks
        hipLaunchKernelGGL(kplane_gather, ggrid, block, 0, stream, pts, tab, ws);
        dim3 cgrid(NPTS / 64u);                              // 8192 blocks
        hipLaunchKernelGGL(kplane_combine, cgrid, block, 0, stream, ws, out);
    } else if (ws_size >= wsB) {
        float2* ws = (float2*)d_ws;
        dim3 grid(16u * (NPTS / 256u));                      // 32768 blocks
        hipLaunchKernelGGL((kplane_pass<0, true >), grid, block, 0, stream, pts, tab, ws);
        hipLaunchKernelGGL((kplane_pass<1, false>), grid, block, 0, stream, pts, tab, ws);
        hipLaunchKernelGGL((kplane_pass<2, false>), grid, block, 0, stream, pts, tab, ws);
        dim3 tgrid((NPTS * 16u) / 256u);
        hipLaunchKernelGGL(kplane_transpose, tgrid, block, 0, stream, ws, out);
    }
}

// Round 4
// 288.220 us; speedup vs baseline: 1.4650x; 1.4650x over previous
//
#include <hip/hip_runtime.h>
#include <stdint.h>

// K-Planes hash-grid encoder, MI355X.
// Request-rate-bound workload (divergent 8B gathers). Round-4 structure:
//  - kplane_lds: levels 0-5 (18 groups). Table footprint (res+1)^2 <= 6561
//    entries (52.5 KB) -> staged to LDS, dense (cx,cy) indexing, hash only
//    at staging. Removes 37.5% of vector-memory gathers.
//  - kplane_hi: levels 6-15 (30 groups), XCD-L2-resident via b&7 map
//    (confirmed r2), even-u0 float4 corner pairing (-25% lane requests).
//  - kplane_combine: multiply 3 planes, LDS transpose, coalesced out.
// Plan B fallback (ws < 201.4 MB): round-2 3-pass + transpose (353 us).

#define NPTS   524288u
#define TSIZE  524288u      // 2^19 entries per (plane,level) table
#define TMASK  0x7FFFFu
#define PRIME1 2654435761u

// floor(16 * 1.3819^l) computed in float64 (matches numpy reference exactly)
__constant__ float c_res[16] = {
    16.f, 22.f, 30.f, 42.f, 58.f, 80.f, 111.f, 153.f,
    212.f, 294.f, 406.f, 561.f, 775.f, 1072.f, 1481.f, 2047.f
};
__constant__ int c_resi[6] = {16, 22, 30, 42, 58, 80};

// hi-kernel slot map: slot = phase*8 + xcd -> group g = plane*16 + lvl,
// levels 6..15 only, dealt round-robin by level so each XCD gets 3-4
// cost-homogeneous groups. 255 = dead slot.
__constant__ uint8_t c_hmap[32] = {
    15, 31, 47, 14, 30, 46, 13, 29,
    45, 28, 44, 12, 11, 27, 43, 10,
    26, 42,  9, 25, 41,  8, 24, 40,
     7, 23, 39,  6, 22, 38, 255, 255
};

// ---------------- levels 0-5: LDS-resident tables ---------------------------
__global__ __launch_bounds__(512) void kplane_lds(
    const float* __restrict__ pts,
    const float2* __restrict__ tab,   // (3, 16, 2^19) float2
    float2* __restrict__ ws)          // (48, NPTS) float2
{
    __shared__ float2 sm[6561];              // 52.5 KB (level-5 worst case)
    const uint32_t b     = blockIdx.x;       // 18 groups x 64 chunks
    const uint32_t gidx  = b >> 6;
    const uint32_t chunk = b & 63u;
    const uint32_t plane = gidx / 6u;
    const uint32_t lvl   = gidx - plane * 6u;
    const uint32_t g     = plane * 16u + lvl;
    const uint32_t R     = (uint32_t)c_resi[lvl] + 1u;
    const uint32_t E     = R * R;
    const float    res   = c_res[lvl];
    const uint32_t base  = g * TSIZE;
    const uint32_t t     = threadIdx.x;

    for (uint32_t i = t; i < E; i += 512u) { // stage touched cells
        const uint32_t cx = i / R;
        const uint32_t cy = i - cx * R;
        sm[i] = tab[base + ((cx ^ (cy * PRIME1)) & TMASK)];
    }
    __syncthreads();

    const uint32_t c0  = (plane == 2u) ? 1u : 0u;
    const uint32_t c1  = (plane == 0u) ? 1u : 2u;
    const uint32_t pt0 = chunk * 8192u + t;  // 16 pts/thread

#pragma unroll 4
    for (uint32_t k = 0; k < 16u; ++k) {
        const uint32_t pt = pt0 + k * 512u;
        const float s0 = pts[pt * 3u + c0] * res;
        const float s1 = pts[pt * 3u + c1] * res;
        const float f0 = floorf(s0);
        const float f1 = floorf(s1);
        const float r0 = s0 - f0;            // exact f32 match to reference
        const float r1 = s1 - f1;
        const uint32_t ci = (uint32_t)f0 * R + (uint32_t)f1;
        const float2 q00 = sm[ci];
        const float2 q01 = sm[ci + 1u];
        const float2 q10 = sm[ci + R];
        const float2 q11 = sm[ci + R + 1u];
        const float w00 = (1.f - r0) * (1.f - r1);
        const float w01 = (1.f - r0) * r1;
        const float w10 = r0 * (1.f - r1);
        const float w11 = r0 * r1;
        ws[g * NPTS + pt] = make_float2(
            w00 * q00.x + w01 * q01.x + w10 * q10.x + w11 * q11.x,
            w00 * q00.y + w01 * q01.y + w10 * q10.y + w11 * q11.y);
    }
}

// ---------------- levels 6-15: L2-resident gather, corner pairing -----------
__global__ __launch_bounds__(256) void kplane_hi(
    const float* __restrict__ pts,
    const float2* __restrict__ tab,
    float2* __restrict__ ws)
{
    const uint32_t b     = blockIdx.x;
    const uint32_t xcd   = b & 7u;
    const uint32_t s     = b >> 3;
    const uint32_t phase = s >> 10;          // 0..3
    const uint32_t chunk = s & 1023u;        // 1024 chunks x 512 pts
    const uint32_t g     = c_hmap[phase * 8u + xcd];
    if (g == 255u) return;
    const uint32_t plane = g >> 4;
    const uint32_t lvl   = g & 15u;
    const float    res   = c_res[lvl];
    const uint32_t c0    = (plane == 2u) ? 1u : 0u;
    const uint32_t c1    = (plane == 0u) ? 1u : 2u;
    const uint32_t base  = g * TSIZE;
    const float4* __restrict__ tab4 = (const float4*)tab;
    const uint32_t b4    = g * (TSIZE / 2u);
    const uint32_t pt0   = chunk * 512u + threadIdx.x;

    float4 P0[2], P1[2];
    float2 Q0[2], Q1[2];
    float  r0[2], r1[2];
    uint32_t sel0[2], sel1[2], oddm[2];

#pragma unroll
    for (int k = 0; k < 2; ++k) {            // issue all loads first
        const uint32_t pt = pt0 + (uint32_t)k * 256u;
        const float s0 = pts[pt * 3u + c0] * res;
        const float s1 = pts[pt * 3u + c1] * res;
        const float f0 = floorf(s0);
        const float f1 = floorf(s1);
        r0[k] = s0 - f0;
        r1[k] = s1 - f1;
        const uint32_t u0  = (uint32_t)f0;
        const uint32_t hy0 = (uint32_t)f1 * PRIME1;
        const uint32_t hy1 = hy0 + PRIME1;
        const uint32_t i00 = ( u0        ^ hy0) & TMASK;
        const uint32_t i01 = ( u0        ^ hy1) & TMASK;
        const uint32_t i10 = ((u0 + 1u)  ^ hy0) & TMASK;
        const uint32_t i11 = ((u0 + 1u)  ^ hy1) & TMASK;
        sel0[k] = i00 & 1u;
        sel1[k] = i01 & 1u;
        oddm[k] = u0 & 1u;
        P0[k] = tab4[b4 + (i00 >> 1)];       // covers t00 (+t10 if u0 even)
        P1[k] = tab4[b4 + (i01 >> 1)];       // covers t01 (+t11 if u0 even)
        Q0[k] = make_float2(0.f, 0.f);
        Q1[k] = make_float2(0.f, 0.f);
        if (oddm[k]) {                       // exec-masked, ~50% lanes
            Q0[k] = tab[base + i10];
            Q1[k] = tab[base + i11];
        }
    }
#pragma unroll
    for (int k = 0; k < 2; ++k) {
        const uint32_t pt = pt0 + (uint32_t)k * 256u;
        const float2 lo0 = make_float2(P0[k].x, P0[k].y);
        const float2 hi0 = make_float2(P0[k].z, P0[k].w);
        const float2 lo1 = make_float2(P1[k].x, P1[k].y);
        const float2 hi1 = make_float2(P1[k].z, P1[k].w);
        const float2 t00 = sel0[k] ? hi0 : lo0;
        const float2 t01 = sel1[k] ? hi1 : lo1;
        const float2 t10 = oddm[k] ? Q0[k] : (sel0[k] ? lo0 : hi0);
        const float2 t11 = oddm[k] ? Q1[k] : (sel1[k] ? lo1 : hi1);
        const float w00 = (1.f - r0[k]) * (1.f - r1[k]);
        const float w01 = (1.f - r0[k]) * r1[k];
        const float w10 = r0[k] * (1.f - r1[k]);
        const float w11 = r0[k] * r1[k];
        ws[g * NPTS + pt] = make_float2(
            w00 * t00.x + w01 * t01.x + w10 * t10.x + w11 * t11.x,
            w00 * t00.y + w01 * t01.y + w10 * t10.y + w11 * t11.y);
    }
}

// ---------------- combine 3 planes, transpose via LDS -----------------------
__global__ __launch_bounds__(256) void kplane_combine(
    const float2* __restrict__ ws,    // (48, NPTS)
    float2* __restrict__ out)         // (NPTS, 16)
{
    __shared__ float2 tile[16][65];
    const uint32_t pt0 = blockIdx.x * 64u;
    const uint32_t t   = threadIdx.x;
    const uint32_t lr  = t >> 6;
    const uint32_t ptl = t & 63u;

#pragma unroll
    for (int k = 0; k < 4; ++k) {
        const uint32_t lvl = (uint32_t)k * 4u + lr;
        const float2 a = ws[( 0u + lvl) * NPTS + pt0 + ptl];
        const float2 b = ws[(16u + lvl) * NPTS + pt0 + ptl];
        const float2 c = ws[(32u + lvl) * NPTS + pt0 + ptl];
        tile[lvl][ptl] = make_float2(a.x * b.x * c.x, a.y * b.y * c.y);
    }
    __syncthreads();
#pragma unroll
    for (int k = 0; k < 4; ++k) {
        const uint32_t e      = t + (uint32_t)k * 256u;
        const uint32_t out_lv = e & 15u;
        const uint32_t out_pt = e >> 4;
        out[(pt0 + out_pt) * 16u + out_lv] = tile[out_lv][out_pt];
    }
}

// ---------------- Plan B fallback: round-2 3-pass + transpose ---------------
template <int P, bool FIRST>
__global__ __launch_bounds__(256) void kplane_pass(
    const float* __restrict__ pts,
    const float2* __restrict__ tab,
    float2* __restrict__ ws)          // (16, NPTS)
{
    const uint32_t b     = blockIdx.x;
    const uint32_t xcd   = b & 7u;
    const uint32_t s     = b >> 3;
    const uint32_t gi    = s >> 11;
    const uint32_t chunk = s & 2047u;
    const uint32_t lvl   = gi * 8u + xcd;
    const uint32_t pt    = chunk * 256u + threadIdx.x;

    constexpr int c0 = (P == 2) ? 1 : 0;
    constexpr int c1 = (P == 0) ? 1 : 2;

    const float a0  = pts[pt * 3u + c0];
    const float a1  = pts[pt * 3u + c1];
    const float res = c_res[lvl];

    const float s0 = a0 * res;
    const float s1 = a1 * res;
    const float f0 = floorf(s0);
    const float f1 = floorf(s1);
    const float r0 = s0 - f0;
    const float r1 = s1 - f1;
    const uint32_t u0 = (uint32_t)f0;
    const uint32_t hy0  = (uint32_t)f1 * PRIME1;
    const uint32_t hy1  = hy0 + PRIME1;
    const uint32_t base = ((uint32_t)P * 16u + lvl) * TSIZE;

    const float2 t00 = tab[base + (( u0       ^ hy0) & TMASK)];
    const float2 t01 = tab[base + (( u0       ^ hy1) & TMASK)];
    const float2 t10 = tab[base + (((u0 + 1u) ^ hy0) & TMASK)];
    const float2 t11 = tab[base + (((u0 + 1u) ^ hy1) & TMASK)];

    const float w00 = (1.f - r0) * (1.f - r1);
    const float w01 = (1.f - r0) * r1;
    const float w10 = r0 * (1.f - r1);
    const float w11 = r0 * r1;

    const float e0 = w00 * t00.x + w01 * t01.x + w10 * t10.x + w11 * t11.x;
    const float e1 = w00 * t00.y + w01 * t01.y + w10 * t10.y + w11 * t11.y;

    const uint32_t widx = lvl * NPTS + pt;
    if (FIRST) {
        ws[widx] = make_float2(e0, e1);
    } else {
        const float2 prev = ws[widx];
        ws[widx] = make_float2(prev.x * e0, prev.y * e1);
    }
}

__global__ __launch_bounds__(256) void kplane_transpose(
    const float2* __restrict__ ws, float2* __restrict__ out)
{
    const uint32_t tid = blockIdx.x * 256u + threadIdx.x;
    const uint32_t lvl = tid & 15u;
    const uint32_t pt  = tid >> 4;
    out[tid] = ws[lvl * NPTS + pt];
}

extern "C" void kernel_launch(void* const* d_in, const int* in_sizes, int n_in,
                              void* d_out, int out_size, void* d_ws, size_t ws_size,
                              hipStream_t stream) {
    const float*  pts = (const float*)d_in[0];
    const float2* tab = (const float2*)d_in[1];
    float2*       out = (float2*)d_out;

    const size_t wsA = (size_t)48 * NPTS * sizeof(float2);   // 201.3 MB
    const size_t wsB = (size_t)16 * NPTS * sizeof(float2);   //  67.1 MB
    dim3 block256(256u), block512(512u);

    if (ws_size >= wsA) {
        float2* ws = (float2*)d_ws;
        dim3 hgrid(4u * 8u * 1024u);                         // 32768 blocks
        hipLaunchKernelGGL(kplane_hi, hgrid, block256, 0, stream, pts, tab, ws);
        dim3 lgrid(18u * 64u);                               // 1152 blocks
        hipLaunchKernelGGL(kplane_lds, lgrid, block512, 0, stream, pts, tab, ws);
        dim3 cgrid(NPTS / 64u);                              // 8192 blocks
        hipLaunchKernelGGL(kplane_combine, cgrid, block256, 0, stream, ws, out);
    } else if (ws_size >= wsB) {
        float2* ws = (float2*)d_ws;
        dim3 grid(16u * (NPTS / 256u));
        hipLaunchKernelGGL((kplane_pass<0, true >), grid, block256, 0, stream, pts, tab, ws);
        hipLaunchKernelGGL((kplane_pass<1, false>), grid, block256, 0, stream, pts, tab, ws);
        hipLaunchKernelGGL((kplane_pass<2, false>), grid, block256, 0, stream, pts, tab, ws);
        dim3 tgrid((NPTS * 16u) / 256u);
        hipLaunchKernelGGL(kplane_transpose, tgrid, block256, 0, stream, ws, out);
    }
}

// Round 5
// 277.225 us; speedup vs baseline: 1.5231x; 1.0397x over previous
//
#include <hip/hip_runtime.h>
#include <stdint.h>

// K-Planes hash-grid encoder, MI355X.
// Empirical invariant (r2-r4): ~2.3 cyc per divergent lane-gather per CU,
// independent of L1 hits -> TA/TCP request-rate bound. Only request-count
// reduction moves the needle.
//  - kplane_lds: levels 0-5 (18 groups), full table in 52.5 KB LDS.
//  - kplane_mid: levels 6-7 (18 stripe-groups), row-striped LDS staging
//    (stripe <= 51 KB), predicated points, ~1 staging req/pt vs 3 direct.
//  - kplane_hi: levels 8-15 (24 groups) = exactly 3 phases x 8 XCDs,
//    XCD-L2-resident (b&7, confirmed r2), even-u0 float4 corner pairing,
//    4 pts/thread MLP.
//  - kplane_combine: multiply 3 planes, LDS transpose, coalesced out.
// Plan B fallback (ws < 201.4 MB): round-2 3-pass + transpose (353 us).

#define NPTS   524288u
#define TSIZE  524288u      // 2^19 entries per (plane,level) table
#define TMASK  0x7FFFFu
#define PRIME1 2654435761u

// floor(16 * 1.3819^l) computed in float64 (matches numpy reference exactly)
__constant__ float c_res[16] = {
    16.f, 22.f, 30.f, 42.f, 58.f, 80.f, 111.f, 153.f,
    212.f, 294.f, 406.f, 561.f, 775.f, 1072.f, 1481.f, 2047.f
};
__constant__ int c_resi[6] = {16, 22, 30, 42, 58, 80};

// mid kernel stripes: local 0-1 = level 6 (R=112), 2-5 = level 7 (R=154).
// membership: lo <= u0 < hiX ; staged rows lo .. min(hiX, R-1).
__constant__ uint16_t c_mid_lo[6]  = {0, 56, 0, 39, 78, 117};
__constant__ uint16_t c_mid_hiX[6] = {56, 112, 39, 78, 117, 154};

// ---------------- levels 0-5: LDS-resident tables ---------------------------
__global__ __launch_bounds__(512) void kplane_lds(
    const float* __restrict__ pts,
    const float2* __restrict__ tab,   // (3, 16, 2^19) float2
    float2* __restrict__ ws)          // (48, NPTS) float2
{
    __shared__ float2 sm[6561];              // 52.5 KB (level-5 worst case)
    const uint32_t b     = blockIdx.x;       // 18 groups x 64 chunks
    const uint32_t gidx  = b >> 6;
    const uint32_t chunk = b & 63u;
    const uint32_t plane = gidx / 6u;
    const uint32_t lvl   = gidx - plane * 6u;
    const uint32_t g     = plane * 16u + lvl;
    const uint32_t R     = (uint32_t)c_resi[lvl] + 1u;
    const uint32_t E     = R * R;
    const float    res   = c_res[lvl];
    const uint32_t base  = g * TSIZE;
    const uint32_t t     = threadIdx.x;

    for (uint32_t i = t; i < E; i += 512u) { // stage touched cells
        const uint32_t cx = i / R;
        const uint32_t cy = i - cx * R;
        sm[i] = tab[base + ((cx ^ (cy * PRIME1)) & TMASK)];
    }
    __syncthreads();

    const uint32_t c0  = (plane == 2u) ? 1u : 0u;
    const uint32_t c1  = (plane == 0u) ? 1u : 2u;
    const uint32_t pt0 = chunk * 8192u + t;  // 16 pts/thread

#pragma unroll 4
    for (uint32_t k = 0; k < 16u; ++k) {
        const uint32_t pt = pt0 + k * 512u;
        const float s0 = pts[pt * 3u + c0] * res;
        const float s1 = pts[pt * 3u + c1] * res;
        const float f0 = floorf(s0);
        const float f1 = floorf(s1);
        const float r0 = s0 - f0;            // exact f32 match to reference
        const float r1 = s1 - f1;
        const uint32_t ci = (uint32_t)f0 * R + (uint32_t)f1;
        const float2 q00 = sm[ci];
        const float2 q01 = sm[ci + 1u];
        const float2 q10 = sm[ci + R];
        const float2 q11 = sm[ci + R + 1u];
        const float w00 = (1.f - r0) * (1.f - r1);
        const float w01 = (1.f - r0) * r1;
        const float w10 = r0 * (1.f - r1);
        const float w11 = r0 * r1;
        ws[g * NPTS + pt] = make_float2(
            w00 * q00.x + w01 * q01.x + w10 * q10.x + w11 * q11.x,
            w00 * q00.y + w01 * q01.y + w10 * q10.y + w11 * q11.y);
    }
}

// ---------------- levels 6-7: row-striped LDS staging -----------------------
__global__ __launch_bounds__(512) void kplane_mid(
    const float* __restrict__ pts,
    const float2* __restrict__ tab,
    float2* __restrict__ ws)
{
    __shared__ float2 sm[6400];              // max stripe 57x112=6384 (51 KB)
    const uint32_t b     = blockIdx.x;       // 18 stripe-groups x 32 chunks
    const uint32_t sg    = b >> 5;
    const uint32_t chunk = b & 31u;
    const uint32_t plane = sg / 6u;
    const uint32_t local = sg - plane * 6u;
    const uint32_t lvl   = (local < 2u) ? 6u : 7u;
    const uint32_t g     = plane * 16u + lvl;
    const uint32_t R     = (lvl == 6u) ? 112u : 154u;
    const uint32_t lo    = c_mid_lo[local];
    const uint32_t hiX   = c_mid_hiX[local];
    const uint32_t nrows = ((hiX < R ? hiX : R - 1u) - lo) + 1u;
    const uint32_t E     = nrows * R;
    const float    res   = c_res[lvl];
    const uint32_t base  = g * TSIZE;
    const uint32_t t     = threadIdx.x;

    for (uint32_t i = t; i < E; i += 512u) { // stage stripe rows lo..lo+nrows-1
        const uint32_t rr = i / R;
        const uint32_t cy = i - rr * R;
        const uint32_t cx = lo + rr;
        sm[i] = tab[base + ((cx ^ (cy * PRIME1)) & TMASK)];
    }
    __syncthreads();

    const uint32_t c0  = (plane == 2u) ? 1u : 0u;
    const uint32_t c1  = (plane == 0u) ? 1u : 2u;
    const uint32_t pt0 = chunk * 16384u + t; // 32 pts/thread, predicated

#pragma unroll 4
    for (uint32_t k = 0; k < 32u; ++k) {
        const uint32_t pt = pt0 + k * 512u;
        const float s0 = pts[pt * 3u + c0] * res;
        const float s1 = pts[pt * 3u + c1] * res;
        const float f0 = floorf(s0);
        const float f1 = floorf(s1);
        const uint32_t u0 = (uint32_t)f0;
        if (u0 >= lo && u0 < hiX) {          // this stripe owns the point
            const float r0 = s0 - f0;
            const float r1 = s1 - f1;
            const uint32_t ci = (u0 - lo) * R + (uint32_t)f1;
            const float2 q00 = sm[ci];
            const float2 q01 = sm[ci + 1u];
            const float2 q10 = sm[ci + R];
            const float2 q11 = sm[ci + R + 1u];
            const float w00 = (1.f - r0) * (1.f - r1);
            const float w01 = (1.f - r0) * r1;
            const float w10 = r0 * (1.f - r1);
            const float w11 = r0 * r1;
            ws[g * NPTS + pt] = make_float2(
                w00 * q00.x + w01 * q01.x + w10 * q10.x + w11 * q11.x,
                w00 * q00.y + w01 * q01.y + w10 * q10.y + w11 * q11.y);
        }
    }
}

// ---------------- levels 8-15: L2-resident gather, corner pairing -----------
__global__ __launch_bounds__(256) void kplane_hi(
    const float* __restrict__ pts,
    const float2* __restrict__ tab,
    float2* __restrict__ ws)
{
    const uint32_t b     = blockIdx.x;
    const uint32_t xcd   = b & 7u;
    const uint32_t s     = b >> 3;
    const uint32_t phase = s >> 9;           // 0..2  (exactly 24 slots)
    const uint32_t chunk = s & 511u;         // 512 chunks x 1024 pts
    const uint32_t plane = phase;
    const uint32_t lvl   = 8u + ((xcd + 3u * phase) & 7u);
    const uint32_t g     = plane * 16u + lvl;
    const float    res   = c_res[lvl];
    const uint32_t c0    = (plane == 2u) ? 1u : 0u;
    const uint32_t c1    = (plane == 0u) ? 1u : 2u;
    const uint32_t base  = g * TSIZE;
    const float4* __restrict__ tab4 = (const float4*)tab;
    const uint32_t b4    = g * (TSIZE / 2u);
    const uint32_t pt0   = chunk * 1024u + threadIdx.x;

    float4 P0[4], P1[4];
    float2 Q0[4], Q1[4];
    float  r0[4], r1[4];
    uint32_t sel0[4], sel1[4], oddm[4];

#pragma unroll
    for (int k = 0; k < 4; ++k) {            // issue all loads first
        const uint32_t pt = pt0 + (uint32_t)k * 256u;
        const float s0 = pts[pt * 3u + c0] * res;
        const float s1 = pts[pt * 3u + c1] * res;
        const float f0 = floorf(s0);
        const float f1 = floorf(s1);
        r0[k] = s0 - f0;
        r1[k] = s1 - f1;
        const uint32_t u0  = (uint32_t)f0;
        const uint32_t hy0 = (uint32_t)f1 * PRIME1;
        const uint32_t hy1 = hy0 + PRIME1;
        const uint32_t i00 = ( u0        ^ hy0) & TMASK;
        const uint32_t i01 = ( u0        ^ hy1) & TMASK;
        const uint32_t i10 = ((u0 + 1u)  ^ hy0) & TMASK;
        const uint32_t i11 = ((u0 + 1u)  ^ hy1) & TMASK;
        sel0[k] = i00 & 1u;
        sel1[k] = i01 & 1u;
        oddm[k] = u0 & 1u;
        P0[k] = tab4[b4 + (i00 >> 1)];       // covers t00 (+t10 if u0 even)
        P1[k] = tab4[b4 + (i01 >> 1)];       // covers t01 (+t11 if u0 even)
        Q0[k] = make_float2(0.f, 0.f);
        Q1[k] = make_float2(0.f, 0.f);
        if (oddm[k]) {                       // exec-masked, ~50% lanes
            Q0[k] = tab[base + i10];
            Q1[k] = tab[base + i11];
        }
    }
#pragma unroll
    for (int k = 0; k < 4; ++k) {
        const uint32_t pt = pt0 + (uint32_t)k * 256u;
        const float2 lo0 = make_float2(P0[k].x, P0[k].y);
        const float2 hi0 = make_float2(P0[k].z, P0[k].w);
        const float2 lo1 = make_float2(P1[k].x, P1[k].y);
        const float2 hi1 = make_float2(P1[k].z, P1[k].w);
        const float2 t00 = sel0[k] ? hi0 : lo0;
        const float2 t01 = sel1[k] ? hi1 : lo1;
        const float2 t10 = oddm[k] ? Q0[k] : (sel0[k] ? lo0 : hi0);
        const float2 t11 = oddm[k] ? Q1[k] : (sel1[k] ? lo1 : hi1);
        const float w00 = (1.f - r0[k]) * (1.f - r1[k]);
        const float w01 = (1.f - r0[k]) * r1[k];
        const float w10 = r0[k] * (1.f - r1[k]);
        const float w11 = r0[k] * r1[k];
        ws[g * NPTS + pt] = make_float2(
            w00 * t00.x + w01 * t01.x + w10 * t10.x + w11 * t11.x,
            w00 * t00.y + w01 * t01.y + w10 * t10.y + w11 * t11.y);
    }
}

// ---------------- combine 3 planes, transpose via LDS -----------------------
__global__ __launch_bounds__(256) void kplane_combine(
    const float2* __restrict__ ws,    // (48, NPTS)
    float2* __restrict__ out)         // (NPTS, 16)
{
    __shared__ float2 tile[16][65];
    const uint32_t pt0 = blockIdx.x * 64u;
    const uint32_t t   = threadIdx.x;
    const uint32_t lr  = t >> 6;
    const uint32_t ptl = t & 63u;

#pragma unroll
    for (int k = 0; k < 4; ++k) {
        const uint32_t lvl = (uint32_t)k * 4u + lr;
        const float2 a = ws[( 0u + lvl) * NPTS + pt0 + ptl];
        const float2 b = ws[(16u + lvl) * NPTS + pt0 + ptl];
        const float2 c = ws[(32u + lvl) * NPTS + pt0 + ptl];
        tile[lvl][ptl] = make_float2(a.x * b.x * c.x, a.y * b.y * c.y);
    }
    __syncthreads();
#pragma unroll
    for (int k = 0; k < 4; ++k) {
        const uint32_t e      = t + (uint32_t)k * 256u;
        const uint32_t out_lv = e & 15u;
        const uint32_t out_pt = e >> 4;
        out[(pt0 + out_pt) * 16u + out_lv] = tile[out_lv][out_pt];
    }
}

// ---------------- Plan B fallback: round-2 3-pass + transpose ---------------
template <int P, bool FIRST>
__global__ __launch_bounds__(256) void kplane_pass(
    const float* __restrict__ pts,
    const float2* __restrict__ tab,
    float2* __restrict__ ws)          // (16, NPTS)
{
    const uint32_t b     = blockIdx.x;
    const uint32_t xcd   = b & 7u;
    const uint32_t s     = b >> 3;
    const uint32_t gi    = s >> 11;
    const uint32_t chunk = s & 2047u;
    const uint32_t lvl   = gi * 8u + xcd;
    const uint32_t pt    = chunk * 256u + threadIdx.x;

    constexpr int c0 = (P == 2) ? 1 : 0;
    constexpr int c1 = (P == 0) ? 1 : 2;

    const float a0  = pts[pt * 3u + c0];
    const float a1  = pts[pt * 3u + c1];
    const float res = c_res[lvl];

    const float s0 = a0 * res;
    const float s1 = a1 * res;
    const float f0 = floorf(s0);
    const float f1 = floorf(s1);
    const float r0 = s0 - f0;
    const float r1 = s1 - f1;
    const uint32_t u0 = (uint32_t)f0;
    const uint32_t hy0  = (uint32_t)f1 * PRIME1;
    const uint32_t hy1  = hy0 + PRIME1;
    const uint32_t base = ((uint32_t)P * 16u + lvl) * TSIZE;

    const float2 t00 = tab[base + (( u0       ^ hy0) & TMASK)];
    const float2 t01 = tab[base + (( u0       ^ hy1) & TMASK)];
    const float2 t10 = tab[base + (((u0 + 1u) ^ hy0) & TMASK)];
    const float2 t11 = tab[base + (((u0 + 1u) ^ hy1) & TMASK)];

    const float w00 = (1.f - r0) * (1.f - r1);
    const float w01 = (1.f - r0) * r1;
    const float w10 = r0 * (1.f - r1);
    const float w11 = r0 * r1;

    const float e0 = w00 * t00.x + w01 * t01.x + w10 * t10.x + w11 * t11.x;
    const float e1 = w00 * t00.y + w01 * t01.y + w10 * t10.y + w11 * t11.y;

    const uint32_t widx = lvl * NPTS + pt;
    if (FIRST) {
        ws[widx] = make_float2(e0, e1);
    } else {
        const float2 prev = ws[widx];
        ws[widx] = make_float2(prev.x * e0, prev.y * e1);
    }
}

__global__ __launch_bounds__(256) void kplane_transpose(
    const float2* __restrict__ ws, float2* __restrict__ out)
{
    const uint32_t tid = blockIdx.x * 256u + threadIdx.x;
    const uint32_t lvl = tid & 15u;
    const uint32_t pt  = tid >> 4;
    out[tid] = ws[lvl * NPTS + pt];
}

extern "C" void kernel_launch(void* const* d_in, const int* in_sizes, int n_in,
                              void* d_out, int out_size, void* d_ws, size_t ws_size,
                              hipStream_t stream) {
    const float*  pts = (const float*)d_in[0];
    const float2* tab = (const float2*)d_in[1];
    float2*       out = (float2*)d_out;

    const size_t wsA = (size_t)48 * NPTS * sizeof(float2);   // 201.3 MB
    const size_t wsB = (size_t)16 * NPTS * sizeof(float2);   //  67.1 MB
    dim3 block256(256u), block512(512u);

    if (ws_size >= wsA) {
        float2* ws = (float2*)d_ws;
        dim3 hgrid(3u * 8u * 512u);                          // 12288 blocks
        hipLaunchKernelGGL(kplane_hi, hgrid, block256, 0, stream, pts, tab, ws);
        dim3 mgrid(18u * 32u);                               // 576 blocks
        hipLaunchKernelGGL(kplane_mid, mgrid, block512, 0, stream, pts, tab, ws);
        dim3 lgrid(18u * 64u);                               // 1152 blocks
        hipLaunchKernelGGL(kplane_lds, lgrid, block512, 0, stream, pts, tab, ws);
        dim3 cgrid(NPTS / 64u);                              // 8192 blocks
        hipLaunchKernelGGL(kplane_combine, cgrid, block256, 0, stream, ws, out);
    } else if (ws_size >= wsB) {
        float2* ws = (float2*)d_ws;
        dim3 grid(16u * (NPTS / 256u));
        hipLaunchKernelGGL((kplane_pass<0, true >), grid, block256, 0, stream, pts, tab, ws);
        hipLaunchKernelGGL((kplane_pass<1, false>), grid, block256, 0, stream, pts, tab, ws);
        hipLaunchKernelGGL((kplane_pass<2, false>), grid, block256, 0, stream, pts, tab, ws);
        dim3 tgrid((NPTS * 16u) / 256u);
        hipLaunchKernelGGL(kplane_transpose, tgrid, block256, 0, stream, ws, out);
    }
}